// Round 10
// baseline (141.448 us; speedup 1.0000x reference)
//
#include <hip/hip_runtime.h>
#include <hip/hip_bf16.h>

#define N_NODES 4096
#define IN_F 512
#define HEADS 8
#define HPH 8
#define HID 64
#define CLS 16
#define NEG_SLOPE 0.2f
#define MAXD 256   // max neighbors stored per node (Binomial(4096,16/4096): P(>256) ~ 0)

__device__ __forceinline__ float leaky(float x) { return x > 0.f ? x : NEG_SLOPE * x; }

// ---- Kernel 1 (heterogeneous, parity-interleaved): even blocks scan 4 adj
// ---- rows (wave=row, memory-latency-bound); odd blocks do proj1 with
// ---- in-block K-quarter split (VALU-bound). Interleaving makes both kinds
// ---- co-resident on every CU from t=0, so the pipes overlap (time~max).
__global__ __launch_bounds__(256, 2) void scan_proj1(
        const int* __restrict__ adj,
        const float* __restrict__ x,
        const float* __restrict__ W1,
        const float* __restrict__ a1l,
        const float* __restrict__ a1r,
        float* __restrict__ g1,
        float* __restrict__ sl1,
        float* __restrict__ sr1,
        int* __restrict__ deg_g,
        int* __restrict__ nbr_g) {
    __shared__ float xs[4][516];          // proj staging; scan branch aliases it
    const int b = blockIdx.x;
    const int t = threadIdx.x;            // 0..255
    if ((b & 1) == 0) {
        // ---------- scan: wave w handles row (b/2)*4+w ----------
        int* nbrS = (int*)&xs[0][0];      // [4][MAXD]
        __shared__ int cntS[4];
        const int w = t >> 6, lane = t & 63;
        if (lane == 0) cntS[w] = 0;       // wave-local init; LDS in-order per wave
        const int i = (b >> 1) * 4 + w;
        const int4* row = (const int4*)(adj + (size_t)i * N_NODES);
#pragma unroll
        for (int pass = 0; pass < 2; ++pass) {
            int4 v[8];
#pragma unroll
            for (int s = 0; s < 8; ++s) v[s] = row[lane + 64 * (pass * 8 + s)];
#pragma unroll
            for (int s = 0; s < 8; ++s) {
                const int base = 4 * (lane + 64 * (pass * 8 + s));
                if (v[s].x | v[s].y | v[s].z | v[s].w) {
                    if (v[s].x) { int p = atomicAdd(&cntS[w], 1); if (p < MAXD) nbrS[w * MAXD + p] = base; }
                    if (v[s].y) { int p = atomicAdd(&cntS[w], 1); if (p < MAXD) nbrS[w * MAXD + p] = base + 1; }
                    if (v[s].z) { int p = atomicAdd(&cntS[w], 1); if (p < MAXD) nbrS[w * MAXD + p] = base + 2; }
                    if (v[s].w) { int p = atomicAdd(&cntS[w], 1); if (p < MAXD) nbrS[w * MAXD + p] = base + 3; }
                }
            }
        }
        const int n = cntS[w] < MAXD ? cntS[w] : MAXD;   // wave-local, in-order
        if (lane == 0) deg_g[i] = n;
        for (int k = lane; k < n; k += 64) nbr_g[(size_t)i * MAXD + k] = nbrS[w * MAXD + k];
        return;
    }
    // ---------- proj1: 4 nodes/block; thread = (node=wave, kq, colgroup) -----
    const int i0 = (b >> 1) * 4;
    const int nl = t >> 6;                // wave = node
    const int inner = t & 63;
    const int kq = inner >> 4;            // K-quarter (0..3)
    const int cg = inner & 15;            // col group (4 cols)
    for (int l = t; l < 512; l += 256) {  // stage 4 x-rows (512 float4)
        const int r = l >> 7, c4 = l & 127;
        *(float4*)&xs[r][c4 * 4] = *(const float4*)(x + (size_t)(i0 + r) * IN_F + c4 * 4);
    }
    __syncthreads();
    float4 acc = make_float4(0.f, 0.f, 0.f, 0.f);
    const float* xrow = &xs[nl][kq * 128];               // LDS broadcast reads
    const float* Wq = W1 + (size_t)(kq * 128) * HID + cg * 4;
#pragma unroll 4
    for (int k = 0; k < 128; k += 4) {
        const float4 xv = *(const float4*)(xrow + k);
        const float4 w0 = *(const float4*)(Wq + (size_t)(k + 0) * HID);
        const float4 w1 = *(const float4*)(Wq + (size_t)(k + 1) * HID);
        const float4 w2 = *(const float4*)(Wq + (size_t)(k + 2) * HID);
        const float4 w3 = *(const float4*)(Wq + (size_t)(k + 3) * HID);
        acc.x += xv.x * w0.x + xv.y * w1.x + xv.z * w2.x + xv.w * w3.x;
        acc.y += xv.x * w0.y + xv.y * w1.y + xv.z * w2.y + xv.w * w3.y;
        acc.z += xv.x * w0.z + xv.y * w1.z + xv.z * w2.z + xv.w * w3.z;
        acc.w += xv.x * w0.w + xv.y * w1.w + xv.z * w2.w + xv.w * w3.w;
    }
    // butterfly-reduce over kq (lane bits 4..5): full g1 in lanes kq==0
#pragma unroll
    for (int m = 16; m <= 32; m <<= 1) {
        acc.x += __shfl_xor(acc.x, m, 64);
        acc.y += __shfl_xor(acc.y, m, 64);
        acc.z += __shfl_xor(acc.z, m, 64);
        acc.w += __shfl_xor(acc.w, m, 64);
    }
    if (kq == 0) {                        // lanes 0..15 of each wave
        const int i = i0 + nl;
        *(float4*)(g1 + (size_t)i * HID + cg * 4) = acc;
        const float4 al = *(const float4*)(a1l + cg * 4);
        const float4 ar = *(const float4*)(a1r + cg * 4);
        float pl = acc.x * al.x + acc.y * al.y + acc.z * al.z + acc.w * al.w;
        float pr = acc.x * ar.x + acc.y * ar.y + acc.z * ar.z + acc.w * ar.w;
        pl += __shfl_xor(pl, 1, 64);      // partner lane cg^1 (same head)
        pr += __shfl_xor(pr, 1, 64);
        if ((cg & 1) == 0) {
            sl1[i * HEADS + (cg >> 1)] = pl;
            sr1[i * HEADS + (cg >> 1)] = pr;
        }
    }
}

// ---- Kernel 2: layer-1 attention + ELU + proj2 (fused). One wave per node. -
// Single full g1/sr1 buffers (3 loads/neighbor). x4 unroll => 8 loads in flight.
__global__ __launch_bounds__(64) void attn1_fused(
        const float* __restrict__ g1,
        const float* __restrict__ sl1,
        const float* __restrict__ sr1,
        const float* __restrict__ W2,
        const float* __restrict__ a2l,
        const float* __restrict__ a2r,
        const int* __restrict__ deg_g,
        const int* __restrict__ nbr_g,
        float* __restrict__ g2,
        float* __restrict__ sl2,
        float* __restrict__ sr2) {
    const int i = blockIdx.x;
    const int t = threadIdx.x;  // c = h*8+d
    __shared__ int nbr[MAXD];
    __shared__ float h1s[HID];
    const int n = deg_g[i];
    for (int k = t; k < n; k += 64) nbr[k] = nbr_g[(size_t)i * MAXD + k];
    __syncthreads();
    const int h = t >> 3;
    const float sl = sl1[i * HEADS + h];
    float denom = 0.f, acc = 0.f;
    int k = 0;
    for (; k + 4 <= n; k += 4) {
        const int j0 = nbr[k], j1 = nbr[k + 1], j2 = nbr[k + 2], j3 = nbr[k + 3];
        const float s0 = sr1[j0 * HEADS + h], s1 = sr1[j1 * HEADS + h];
        const float s2 = sr1[j2 * HEADS + h], s3 = sr1[j3 * HEADS + h];
        const float v0 = g1[(size_t)j0 * HID + t], v1 = g1[(size_t)j1 * HID + t];
        const float v2 = g1[(size_t)j2 * HID + t], v3 = g1[(size_t)j3 * HID + t];
        const float w0 = __expf(leaky(sl + s0)), w1 = __expf(leaky(sl + s1));
        const float w2 = __expf(leaky(sl + s2)), w3 = __expf(leaky(sl + s3));
        denom += (w0 + w1) + (w2 + w3);
        acc += w0 * v0; acc += w1 * v1; acc += w2 * v2; acc += w3 * v3;
    }
    for (; k < n; ++k) {
        const int jj = nbr[k];
        const float w = __expf(leaky(sl + sr1[jj * HEADS + h]));
        denom += w;
        acc += w * g1[(size_t)jj * HID + t];
    }
    float o = (n > 0) ? (acc / denom) : 0.f;
    o = (o > 0.f) ? o : expm1f(o);            // ELU
    h1s[t] = o;
    __syncthreads();
    // proj2: g2[i][c] = sum_k h1s[k] * W2[k][c]; lane t = (quarter q, class c)
    const int q = t >> 4, c = t & 15;
    float p = 0.f;
#pragma unroll
    for (int kk = 0; kk < 16; ++kk) {
        const int k2 = q * 16 + kk;
        p += h1s[k2] * W2[k2 * CLS + c];
    }
    p += __shfl_xor(p, 16, 64);
    p += __shfl_xor(p, 32, 64);
    float pl = 0.f, pr = 0.f;
    if (t < CLS) {
        g2[(size_t)i * CLS + t] = p;
        pl = p * a2l[t];
        pr = p * a2r[t];
    }
#pragma unroll
    for (int off = 1; off < 16; off <<= 1) {
        pl += __shfl_xor(pl, off, 64);
        pr += __shfl_xor(pr, off, 64);
    }
    if (t == 0) { sl2[i] = pl; sr2[i] = pr; }
}

// ---- Kernel 3: layer-2 attention -> fp32 out. 4 nodes/block, x4 unroll. ----
__global__ __launch_bounds__(64) void attn2(
        const int* __restrict__ deg_g,
        const int* __restrict__ nbr_g,
        const float* __restrict__ g2,
        const float* __restrict__ sl2,
        const float* __restrict__ sr2,
        float* __restrict__ out) {
    const int t = threadIdx.x;          // 0..63
    const int g = t >> 4;               // node group 0..3
    const int c = t & 15;               // class
    const int node = blockIdx.x * 4 + g;
    __shared__ int nbrs[4][MAXD];
    const int n = deg_g[node];
    for (int k = c; k < n; k += 16) nbrs[g][k] = nbr_g[(size_t)node * MAXD + k];
    __syncthreads();
    const float sl = sl2[node];
    float denom = 0.f, acc = 0.f;
    int k = 0;
    for (; k + 4 <= n; k += 4) {
        const int j0 = nbrs[g][k], j1 = nbrs[g][k + 1];
        const int j2 = nbrs[g][k + 2], j3 = nbrs[g][k + 3];
        const float s0 = sr2[j0], s1 = sr2[j1], s2 = sr2[j2], s3 = sr2[j3];
        const float v0 = g2[(size_t)j0 * CLS + c], v1 = g2[(size_t)j1 * CLS + c];
        const float v2 = g2[(size_t)j2 * CLS + c], v3 = g2[(size_t)j3 * CLS + c];
        const float w0 = __expf(leaky(sl + s0)), w1 = __expf(leaky(sl + s1));
        const float w2 = __expf(leaky(sl + s2)), w3 = __expf(leaky(sl + s3));
        denom += (w0 + w1) + (w2 + w3);
        acc += w0 * v0; acc += w1 * v1; acc += w2 * v2; acc += w3 * v3;
    }
    for (; k < n; ++k) {
        const int jj = nbrs[g][k];
        const float w = __expf(leaky(sl + sr2[jj]));
        denom += w;
        acc += w * g2[(size_t)jj * CLS + c];
    }
    out[(size_t)node * CLS + c] = (n > 0) ? acc / denom : 0.f;
}

extern "C" void kernel_launch(void* const* d_in, const int* in_sizes, int n_in,
                              void* d_out, int out_size, void* d_ws, size_t ws_size,
                              hipStream_t stream) {
    const float* x   = (const float*)d_in[0];
    const int*   adj = (const int*)d_in[1];
    const float* W1  = (const float*)d_in[2];
    const float* a1l = (const float*)d_in[3];
    const float* a1r = (const float*)d_in[4];
    const float* W2  = (const float*)d_in[5];
    const float* a2l = (const float*)d_in[6];
    const float* a2r = (const float*)d_in[7];
    float* out = (float*)d_out;

    float* ws  = (float*)d_ws;
    float* g1  = ws;                                  // 4096*64
    float* sl1 = g1  + (size_t)N_NODES * HID;         // 4096*8
    float* sr1 = sl1 + (size_t)N_NODES * HEADS;
    float* g2  = sr1 + (size_t)N_NODES * HEADS;       // 4096*16
    float* sl2 = g2  + (size_t)N_NODES * CLS;         // 4096
    float* sr2 = sl2 + N_NODES;
    int*   deg = (int*)(sr2 + N_NODES);               // 4096
    int*   nbr = deg + N_NODES;                       // 4096*MAXD (4 MB)

    scan_proj1<<<2 * (N_NODES / 4), 256, 0, stream>>>(
        adj, x, W1, a1l, a1r, g1, sl1, sr1, deg, nbr);
    attn1_fused<<<N_NODES, 64, 0, stream>>>(g1, sl1, sr1, W2, a2l, a2r,
                                            deg, nbr, g2, sl2, sr2);
    attn2<<<N_NODES / 4, 64, 0, stream>>>(deg, nbr, g2, sl2, sr2, out);
}

// Round 11
// 138.643 us; speedup vs baseline: 1.0202x; 1.0202x over previous
//
#include <hip/hip_runtime.h>
#include <hip/hip_bf16.h>

#define N_NODES 4096
#define IN_F 512
#define HEADS 8
#define HPH 8
#define HID 64
#define CLS 16
#define NEG_SLOPE 0.2f
#define MAXD 256   // max neighbors stored per node (Binomial(4096,16/4096): P(>256) ~ 0)

__device__ __forceinline__ float leaky(float x) { return x > 0.f ? x : NEG_SLOPE * x; }

// ---- Kernel 1: adjacency scan. 1024 blocks x 256 thr; wave = one adj row. --
// 2 passes x 8 int4 in flight per lane. 16 waves/CU when fully resident.
__global__ __launch_bounds__(256) void scan(const int* __restrict__ adj,
                                            int* __restrict__ deg_g,
                                            int* __restrict__ nbr_g) {
    __shared__ int nbrS[4][MAXD];
    __shared__ int cntS[4];
    const int t = threadIdx.x;
    const int w = t >> 6, lane = t & 63;
    if (lane == 0) cntS[w] = 0;           // wave-local; LDS ops in-order per wave
    const int i = blockIdx.x * 4 + w;
    const int4* row = (const int4*)(adj + (size_t)i * N_NODES);
#pragma unroll
    for (int pass = 0; pass < 2; ++pass) {
        int4 v[8];
#pragma unroll
        for (int s = 0; s < 8; ++s) v[s] = row[lane + 64 * (pass * 8 + s)];
#pragma unroll
        for (int s = 0; s < 8; ++s) {
            const int base = 4 * (lane + 64 * (pass * 8 + s));
            if (v[s].x | v[s].y | v[s].z | v[s].w) {
                if (v[s].x) { int p = atomicAdd(&cntS[w], 1); if (p < MAXD) nbrS[w][p] = base; }
                if (v[s].y) { int p = atomicAdd(&cntS[w], 1); if (p < MAXD) nbrS[w][p] = base + 1; }
                if (v[s].z) { int p = atomicAdd(&cntS[w], 1); if (p < MAXD) nbrS[w][p] = base + 2; }
                if (v[s].w) { int p = atomicAdd(&cntS[w], 1); if (p < MAXD) nbrS[w][p] = base + 3; }
            }
        }
    }
    const int n = cntS[w] < MAXD ? cntS[w] : MAXD;
    if (lane == 0) deg_g[i] = n;
    for (int k = lane; k < n; k += 64) nbr_g[(size_t)i * MAXD + k] = nbrS[w][k];
}

// ---- Kernel 2: proj1 g1 = x @ W1 + scores, FULL output ---------------------
// 256 blocks x 256 thr; block = 16 nodes, thread = (node, 4 cols), full K.
// Per W1 load instr: 16 cg-lanes cover 256B, 4 node-groups broadcast-share ->
// block W1 traffic = 128 KB, chip total 32 MB (vs 512 MB in the R9/R10 form).
__global__ __launch_bounds__(256, 2) void proj1(const float* __restrict__ x,
                                                const float* __restrict__ W1,
                                                const float* __restrict__ a1l,
                                                const float* __restrict__ a1r,
                                                float* __restrict__ g1,
                                                float* __restrict__ sl1,
                                                float* __restrict__ sr1) {
    const int t  = threadIdx.x;          // 0..255
    const int nl = t >> 4;               // node 0..15
    const int cg = t & 15;               // col group (4 cols)
    const int i0 = blockIdx.x * 16;
    __shared__ float xs[16][516];        // 32KB + pad
    for (int l = t; l < 16 * IN_F / 4; l += 256) {   // 2048 float4, 8/thread
        const int r = l >> 7, c4 = l & 127;
        *(float4*)&xs[r][c4 * 4] = *(const float4*)(x + (size_t)(i0 + r) * IN_F + c4 * 4);
    }
    __syncthreads();
    float4 acc = make_float4(0.f, 0.f, 0.f, 0.f);
    const float* xrow = &xs[nl][0];
    const float* Wc = W1 + cg * 4;
#pragma unroll 4
    for (int k = 0; k < IN_F; k += 4) {
        const float4 xv = *(const float4*)(xrow + k);   // broadcast across cg lanes
        const float4 w0 = *(const float4*)(Wc + (size_t)(k + 0) * HID);
        const float4 w1 = *(const float4*)(Wc + (size_t)(k + 1) * HID);
        const float4 w2 = *(const float4*)(Wc + (size_t)(k + 2) * HID);
        const float4 w3 = *(const float4*)(Wc + (size_t)(k + 3) * HID);
        acc.x += xv.x * w0.x + xv.y * w1.x + xv.z * w2.x + xv.w * w3.x;
        acc.y += xv.x * w0.y + xv.y * w1.y + xv.z * w2.y + xv.w * w3.y;
        acc.z += xv.x * w0.z + xv.y * w1.z + xv.z * w2.z + xv.w * w3.z;
        acc.w += xv.x * w0.w + xv.y * w1.w + xv.z * w2.w + xv.w * w3.w;
    }
    const int i = i0 + nl;
    *(float4*)(g1 + (size_t)i * HID + cg * 4) = acc;
    const float4 al = *(const float4*)(a1l + cg * 4);
    const float4 ar = *(const float4*)(a1r + cg * 4);
    float pl = acc.x * al.x + acc.y * al.y + acc.z * al.z + acc.w * al.w;
    float pr = acc.x * ar.x + acc.y * ar.y + acc.z * ar.z + acc.w * ar.w;
    pl += __shfl_xor(pl, 1, 64);         // partner lane t^1: same node, other
    pr += __shfl_xor(pr, 1, 64);         // half of head (cg pairs)
    if ((cg & 1) == 0) {
        sl1[i * HEADS + (cg >> 1)] = pl;
        sr1[i * HEADS + (cg >> 1)] = pr;
    }
}

// ---- Kernel 3: layer-1 attention + ELU + proj2 (fused). One wave per node. -
// Full g1/sr1 buffers (3 loads/neighbor). x4 unroll => 8 loads in flight.
__global__ __launch_bounds__(64) void attn1_fused(
        const float* __restrict__ g1,
        const float* __restrict__ sl1,
        const float* __restrict__ sr1,
        const float* __restrict__ W2,
        const float* __restrict__ a2l,
        const float* __restrict__ a2r,
        const int* __restrict__ deg_g,
        const int* __restrict__ nbr_g,
        float* __restrict__ g2,
        float* __restrict__ sl2,
        float* __restrict__ sr2) {
    const int i = blockIdx.x;
    const int t = threadIdx.x;  // c = h*8+d
    __shared__ int nbr[MAXD];
    __shared__ float h1s[HID];
    const int n = deg_g[i];
    for (int k = t; k < n; k += 64) nbr[k] = nbr_g[(size_t)i * MAXD + k];
    __syncthreads();
    const int h = t >> 3;
    const float sl = sl1[i * HEADS + h];
    float denom = 0.f, acc = 0.f;
    int k = 0;
    for (; k + 4 <= n; k += 4) {
        const int j0 = nbr[k], j1 = nbr[k + 1], j2 = nbr[k + 2], j3 = nbr[k + 3];
        const float s0 = sr1[j0 * HEADS + h], s1 = sr1[j1 * HEADS + h];
        const float s2 = sr1[j2 * HEADS + h], s3 = sr1[j3 * HEADS + h];
        const float v0 = g1[(size_t)j0 * HID + t], v1 = g1[(size_t)j1 * HID + t];
        const float v2 = g1[(size_t)j2 * HID + t], v3 = g1[(size_t)j3 * HID + t];
        const float w0 = __expf(leaky(sl + s0)), w1 = __expf(leaky(sl + s1));
        const float w2 = __expf(leaky(sl + s2)), w3 = __expf(leaky(sl + s3));
        denom += (w0 + w1) + (w2 + w3);
        acc += w0 * v0; acc += w1 * v1; acc += w2 * v2; acc += w3 * v3;
    }
    for (; k < n; ++k) {
        const int jj = nbr[k];
        const float w = __expf(leaky(sl + sr1[jj * HEADS + h]));
        denom += w;
        acc += w * g1[(size_t)jj * HID + t];
    }
    float o = (n > 0) ? (acc / denom) : 0.f;
    o = (o > 0.f) ? o : expm1f(o);            // ELU
    h1s[t] = o;
    __syncthreads();
    // proj2: g2[i][c] = sum_k h1s[k] * W2[k][c]; lane t = (quarter q, class c)
    const int q = t >> 4, c = t & 15;
    float p = 0.f;
#pragma unroll
    for (int kk = 0; kk < 16; ++kk) {
        const int k2 = q * 16 + kk;
        p += h1s[k2] * W2[k2 * CLS + c];
    }
    p += __shfl_xor(p, 16, 64);
    p += __shfl_xor(p, 32, 64);
    float pl = 0.f, pr = 0.f;
    if (t < CLS) {
        g2[(size_t)i * CLS + t] = p;
        pl = p * a2l[t];
        pr = p * a2r[t];
    }
#pragma unroll
    for (int off = 1; off < 16; off <<= 1) {
        pl += __shfl_xor(pl, off, 64);
        pr += __shfl_xor(pr, off, 64);
    }
    if (t == 0) { sl2[i] = pl; sr2[i] = pr; }
}

// ---- Kernel 4: layer-2 attention -> fp32 out. 4 nodes/block, x4 unroll. ----
__global__ __launch_bounds__(64) void attn2(
        const int* __restrict__ deg_g,
        const int* __restrict__ nbr_g,
        const float* __restrict__ g2,
        const float* __restrict__ sl2,
        const float* __restrict__ sr2,
        float* __restrict__ out) {
    const int t = threadIdx.x;          // 0..63
    const int g = t >> 4;               // node group 0..3
    const int c = t & 15;               // class
    const int node = blockIdx.x * 4 + g;
    __shared__ int nbrs[4][MAXD];
    const int n = deg_g[node];
    for (int k = c; k < n; k += 16) nbrs[g][k] = nbr_g[(size_t)node * MAXD + k];
    __syncthreads();
    const float sl = sl2[node];
    float denom = 0.f, acc = 0.f;
    int k = 0;
    for (; k + 4 <= n; k += 4) {
        const int j0 = nbrs[g][k], j1 = nbrs[g][k + 1];
        const int j2 = nbrs[g][k + 2], j3 = nbrs[g][k + 3];
        const float s0 = sr2[j0], s1 = sr2[j1], s2 = sr2[j2], s3 = sr2[j3];
        const float v0 = g2[(size_t)j0 * CLS + c], v1 = g2[(size_t)j1 * CLS + c];
        const float v2 = g2[(size_t)j2 * CLS + c], v3 = g2[(size_t)j3 * CLS + c];
        const float w0 = __expf(leaky(sl + s0)), w1 = __expf(leaky(sl + s1));
        const float w2 = __expf(leaky(sl + s2)), w3 = __expf(leaky(sl + s3));
        denom += (w0 + w1) + (w2 + w3);
        acc += w0 * v0; acc += w1 * v1; acc += w2 * v2; acc += w3 * v3;
    }
    for (; k < n; ++k) {
        const int jj = nbrs[g][k];
        const float w = __expf(leaky(sl + sr2[jj]));
        denom += w;
        acc += w * g2[(size_t)jj * CLS + c];
    }
    out[(size_t)node * CLS + c] = (n > 0) ? acc / denom : 0.f;
}

extern "C" void kernel_launch(void* const* d_in, const int* in_sizes, int n_in,
                              void* d_out, int out_size, void* d_ws, size_t ws_size,
                              hipStream_t stream) {
    const float* x   = (const float*)d_in[0];
    const int*   adj = (const int*)d_in[1];
    const float* W1  = (const float*)d_in[2];
    const float* a1l = (const float*)d_in[3];
    const float* a1r = (const float*)d_in[4];
    const float* W2  = (const float*)d_in[5];
    const float* a2l = (const float*)d_in[6];
    const float* a2r = (const float*)d_in[7];
    float* out = (float*)d_out;

    float* ws  = (float*)d_ws;
    float* g1  = ws;                                  // 4096*64
    float* sl1 = g1  + (size_t)N_NODES * HID;         // 4096*8
    float* sr1 = sl1 + (size_t)N_NODES * HEADS;
    float* g2  = sr1 + (size_t)N_NODES * HEADS;       // 4096*16
    float* sl2 = g2  + (size_t)N_NODES * CLS;         // 4096
    float* sr2 = sl2 + N_NODES;
    int*   deg = (int*)(sr2 + N_NODES);               // 4096
    int*   nbr = deg + N_NODES;                       // 4096*MAXD (4 MB)

    scan<<<N_NODES / 4, 256, 0, stream>>>(adj, deg, nbr);
    proj1<<<N_NODES / 16, 256, 0, stream>>>(x, W1, a1l, a1r, g1, sl1, sr1);
    attn1_fused<<<N_NODES, 64, 0, stream>>>(g1, sl1, sr1, W2, a2l, a2r,
                                            deg, nbr, g2, sl2, sr2);
    attn2<<<N_NODES / 4, 64, 0, stream>>>(deg, nbr, g2, sl2, sr2, out);
}